// Round 10
// baseline (1036.816 us; speedup 1.0000x reference)
//
#include <hip/hip_runtime.h>
#include <stdint.h>

#define NB 8
#define NPTS 4096
#define NPOINT 1024
#define NSAMPLE 32
#define FCH 64
#define HID 128
#define CAPW 160  // per-wave candidate capacity (1024-pt segment, expected ~15)

typedef unsigned long long ull;

// d2 computed with EXACT numpy rounding/order: ((dx*dx + dy*dy) + dz*dz),
// no FMA contraction (FPS argmax + radius selection must match ref bitwise).
__device__ __forceinline__ float d2_exact(float ax, float ay, float az,
                                          float bx, float by, float bz) {
  float dx = ax - bx, dy = ay - by, dz = az - bz;
  return __fadd_rn(__fadd_rn(__fmul_rn(dx, dx), __fmul_rn(dy, dy)),
                   __fmul_rn(dz, dz));
}

// DPP f32 max step (identity 0 valid: dists >= 0). VALU pipe.
#define DPPMAX(v, ctrl)                                                     \
  v = fmaxf(v, __int_as_float(__builtin_amdgcn_update_dpp(                  \
                 0, __float_as_int(v), ctrl, 0xf, 0xf, true)))

// ---------------- shared memory ---------------------------------------------
// >80KB LDS -> hardware guarantees 1 block/CU (no mapping assumptions, the
// R9 companion-exit trick was dispatch-order dependent). Producers get solo
// CUs structurally; consumer blocks carry 8 waves = the TLP R4 lacked.
struct ProdS {
  float4 pts[NPTS];     // 64 KB
  float chunk[64 * 3];  // 64-centroid publish buffer
  float wkd[2][8];      // per-wave max dist (parity dbuf), 8 waves
  int wki[2][8];        // per-wave argmax idx
};
struct ConsHalf {  // one R4-style query pipeline (4 waves)
  float fin[32][68];  // dxyz 0..2, feats 3..66, pad 67
  float fm[HID];
  int sidx[NSAMPLE];
  int scnt[4];
  union {  // knn candidates overlaid on GEMM buffers (dead during knn)
    float bufA[32][HID];  // h1 then h2
    ull candseg[4][CAPW];
  };
  union {
    float fp[32][HID];  // f_prime
    ull cand2[4 * CAPW];
  };
};
struct ConsS {
  ConsHalf h[2];  // waves 0-3 -> h[0], waves 4-7 -> h[1]
  int tkbase;
};
union SMemU {
  ProdS p;
  ConsS c;
  unsigned char pad_[90112];  // 88KB > 80KB -> 1 block/CU guaranteed
};

// ---------------------------------------------------------------- FPS
// R3/R4-proven chain widened to 8 waves: 8 pts/thread halves the dominant
// update-loop issue time. Publishes centroids in 64-chunks (flush stores +
// threadfence, barrier, release-store of progress[b]). Runs at prio 3.
__device__ void run_fps(const float* __restrict__ xyz,
                        float* __restrict__ newxyz, int* progress, int b,
                        ProdS& S) {
  __builtin_amdgcn_s_setprio(3);
  const int t = threadIdx.x;
  const int wid = t >> 6;
  const float* src = xyz + (size_t)b * NPTS * 3;
  float* dstb = newxyz + (size_t)b * NPOINT * 3;
  for (int j = t; j < NPTS; j += 512) {
    const float* p = src + 3 * j;
    S.pts[j] = make_float4(p[0], p[1], p[2], 0.f);
  }
  __syncthreads();
  const int base = t * 8;
  float px[8], py[8], pz[8], dist[8];
  const float4 c0 = S.pts[0];
  float bv = -INFINITY;
  int br = 0;
#pragma unroll
  for (int r = 0; r < 8; ++r) {
    float4 p = S.pts[base + r];
    px[r] = p.x; py[r] = p.y; pz[r] = p.z;
    dist[r] = d2_exact(px[r], py[r], pz[r], c0.x, c0.y, c0.z);
    bool c = dist[r] > bv;  // strict > keeps lowest r (idx) on ties
    bv = c ? dist[r] : bv;
    br = c ? r : br;
  }
  if (t == 0) {
    S.chunk[0] = c0.x; S.chunk[1] = c0.y; S.chunk[2] = c0.z;
  }
  for (int it = 1; it < NPOINT; ++it) {
    float wm = bv;
    DPPMAX(wm, 0x111); DPPMAX(wm, 0x112); DPPMAX(wm, 0x114); DPPMAX(wm, 0x118);
    DPPMAX(wm, 0x142); DPPMAX(wm, 0x143);
    float gmaxw =
        __int_as_float(__builtin_amdgcn_readlane(__float_as_int(wm), 63));
    ull m = __ballot(bv == gmaxw);
    int lead = __ffsll((long long)m) - 1;  // lowest lane == lowest index
    int widx = __builtin_amdgcn_readlane(base + br, lead);
    const int par = it & 1;
    if ((t & 63) == 0) {
      S.wkd[par][wid] = gmaxw;
      S.wki[par][wid] = widx;
    }
    __syncthreads();  // parity double-buffer -> single barrier/iter
    if ((it & 63) == 0) {
      if (t < 192) {
        dstb[(it - 64) * 3 + t] = S.chunk[t];
        __threadfence();
      }
      __syncthreads();
      if (t == 0)
        __hip_atomic_store(&progress[b], it, __ATOMIC_RELEASE,
                           __HIP_MEMORY_SCOPE_AGENT);
    }
    // combine 8 wave keys (max dist, ties -> lowest index)
    float4 dlo = *(const float4*)&S.wkd[par][0];
    float4 dhi = *(const float4*)&S.wkd[par][4];
    int4 ilo = *(const int4*)&S.wki[par][0];
    int4 ihi = *(const int4*)&S.wki[par][4];
    float d = dlo.x;
    int fi = ilo.x;
#define CMB(dd, ii)                                   \
  {                                                   \
    bool c_ = (dd > d) || (dd == d && ii < fi);       \
    d = c_ ? dd : d;                                  \
    fi = c_ ? ii : fi;                                \
  }
    CMB(dlo.y, ilo.y) CMB(dlo.z, ilo.z) CMB(dlo.w, ilo.w)
    CMB(dhi.x, ihi.x) CMB(dhi.y, ihi.y) CMB(dhi.z, ihi.z) CMB(dhi.w, ihi.w)
#undef CMB
    const float4 cp = S.pts[fi];
    if (t == 0) {
      int slot = (it & 63) * 3;
      S.chunk[slot + 0] = cp.x;
      S.chunk[slot + 1] = cp.y;
      S.chunk[slot + 2] = cp.z;
    }
    bv = -INFINITY;
    br = 0;
#pragma unroll
    for (int r = 0; r < 8; ++r) {
      float dnew = d2_exact(px[r], py[r], pz[r], cp.x, cp.y, cp.z);
      float nd = fminf(dist[r], dnew);
      dist[r] = nd;
      bool c = nd > bv;
      bv = c ? nd : bv;
      br = c ? r : br;
    }
  }
  __syncthreads();  // chunk holds centroids [960,1024)
  if (t < 192) {
    dstb[(NPOINT - 64) * 3 + t] = S.chunk[t];
    __threadfence();
  }
  __syncthreads();
  if (t == 0)
    __hip_atomic_store(&progress[b], NPOINT, __ATOMIC_RELEASE,
                       __HIP_MEMORY_SCOPE_AGENT);
  __builtin_amdgcn_s_setprio(0);
}

// ---------------------------------------------------------------- MLP gemms
// R4's plain streamed-W loops (R7: compiler pipelines these better than
// manual rotation; R2: no LDS staging of W).
template <int K>
__device__ __forceinline__ void gemm_tile(const float* __restrict__ a0,
                                          const float* __restrict__ a1,
                                          const float* __restrict__ a2,
                                          const float* __restrict__ a3,
                                          const float* __restrict__ W,
                                          float acc[4][4]) {
  int k = 0;
  for (; k + 4 <= K; k += 4) {
    float4 A0 = *(const float4*)(a0 + k);
    float4 A1 = *(const float4*)(a1 + k);
    float4 A2 = *(const float4*)(a2 + k);
    float4 A3 = *(const float4*)(a3 + k);
#pragma unroll
    for (int kk = 0; kk < 4; ++kk) {
      float4 w = *(const float4*)(W + (size_t)(k + kk) * HID);
      float e0 = (&A0.x)[kk], e1 = (&A1.x)[kk], e2 = (&A2.x)[kk], e3 = (&A3.x)[kk];
      acc[0][0] += e0 * w.x; acc[0][1] += e0 * w.y; acc[0][2] += e0 * w.z; acc[0][3] += e0 * w.w;
      acc[1][0] += e1 * w.x; acc[1][1] += e1 * w.y; acc[1][2] += e1 * w.z; acc[1][3] += e1 * w.w;
      acc[2][0] += e2 * w.x; acc[2][1] += e2 * w.y; acc[2][2] += e2 * w.z; acc[2][3] += e2 * w.w;
      acc[3][0] += e3 * w.x; acc[3][1] += e3 * w.y; acc[3][2] += e3 * w.z; acc[3][3] += e3 * w.w;
    }
  }
  for (; k < K; ++k) {
    float4 w = *(const float4*)(W + (size_t)k * HID);
    float e0 = a0[k], e1 = a1[k], e2 = a2[k], e3 = a3[k];
    acc[0][0] += e0 * w.x; acc[0][1] += e0 * w.y; acc[0][2] += e0 * w.z; acc[0][3] += e0 * w.w;
    acc[1][0] += e1 * w.x; acc[1][1] += e1 * w.y; acc[1][2] += e1 * w.z; acc[1][3] += e1 * w.w;
    acc[2][0] += e2 * w.x; acc[2][1] += e2 * w.y; acc[2][2] += e2 * w.z; acc[2][3] += e2 * w.w;
    acc[3][0] += e3 * w.x; acc[3][1] += e3 * w.y; acc[3][2] += e3 * w.z; acc[3][3] += e3 * w.w;
  }
}

__device__ __forceinline__ void gemm_tile_corr(const float* __restrict__ a0,
                                               const float* __restrict__ a1,
                                               const float* __restrict__ a2,
                                               const float* __restrict__ a3,
                                               const float* __restrict__ W,
                                               const float* __restrict__ fm,
                                               float acc[4][4], float corr[4]) {
  for (int k = 0; k < HID; k += 4) {
    float4 A0 = *(const float4*)(a0 + k);
    float4 A1 = *(const float4*)(a1 + k);
    float4 A2 = *(const float4*)(a2 + k);
    float4 A3 = *(const float4*)(a3 + k);
    float4 FM = *(const float4*)(fm + k);
#pragma unroll
    for (int kk = 0; kk < 4; ++kk) {
      float4 w = *(const float4*)(W + (size_t)(k + kk) * HID);
      float e0 = (&A0.x)[kk], e1 = (&A1.x)[kk], e2 = (&A2.x)[kk], e3 = (&A3.x)[kk];
      float cf = (&FM.x)[kk];
      acc[0][0] += e0 * w.x; acc[0][1] += e0 * w.y; acc[0][2] += e0 * w.z; acc[0][3] += e0 * w.w;
      acc[1][0] += e1 * w.x; acc[1][1] += e1 * w.y; acc[1][2] += e1 * w.z; acc[1][3] += e1 * w.w;
      acc[2][0] += e2 * w.x; acc[2][1] += e2 * w.y; acc[2][2] += e2 * w.z; acc[2][3] += e2 * w.w;
      acc[3][0] += e3 * w.x; acc[3][1] += e3 * w.y; acc[3][2] += e3 * w.z; acc[3][3] += e3 * w.w;
      corr[0] += cf * w.x; corr[1] += cf * w.y; corr[2] += cf * w.z; corr[3] += cf * w.w;
    }
  }
}

// ---------------------------------------------------------------- consumer
// 512 threads = 2 independent R4-style 4-wave pipelines (h[0]: t<256,
// h[1]: t>=256), identical per-wave work to R4 (R6 lesson: don't shrink the
// tile). All __syncthreads are block-wide and hit by both halves at the
// same static points.
__device__ void run_consumer(const float* __restrict__ xyz,
                             const float* __restrict__ feats,
                             const float* __restrict__ W1f,
                             const float* __restrict__ b1f,
                             const float* __restrict__ W2f,
                             const float* __restrict__ b2f,
                             const float* __restrict__ W1w,
                             const float* __restrict__ b1w,
                             const float* __restrict__ W2w,
                             const float* __restrict__ b2w,
                             const float* __restrict__ newxyz,
                             float* __restrict__ fout, int* progress,
                             int* ticket, ConsS& S) {
  const int t = threadIdx.x;
  const int hid = t >> 8;    // half 0/1
  const int ht = t & 255;    // thread within half
  const int wv = ht >> 6;    // wave within half (0..3)
  const int lane = t & 63;
  const float r2 = 0.0225f;  // np float32(RADIUS**2)
  ConsHalf& H = S.h[hid];

  while (true) {
    if (t == 0) S.tkbase = atomicAdd(ticket, 2);
    __syncthreads();
    const int tkb = S.tkbase;
    if (tkb >= NB * NPOINT) return;  // 8192 even, tkb even -> both valid
    const int tk = tkb + hid;
    const int it = tk >> 3;
    const int b = tk & 7;
    const int g = b * NPOINT + it;

    // wait until centroid `it` of batch b is published (one scout per half)
    if (ht == 0) {
      while (__hip_atomic_load(&progress[b], __ATOMIC_RELAXED,
                               __HIP_MEMORY_SCOPE_AGENT) <= it)
        __builtin_amdgcn_s_sleep(32);
    }
    __syncthreads();
    {  // every thread acquires its half's progress word
      int pv = __hip_atomic_load(&progress[b], __ATOMIC_ACQUIRE,
                                 __HIP_MEMORY_SCOPE_AGENT);
      while (pv <= it) {
        __builtin_amdgcn_s_sleep(8);
        pv = __hip_atomic_load(&progress[b], __ATOMIC_ACQUIRE,
                               __HIP_MEMORY_SCOPE_AGENT);
      }
    }
    const float cx = newxyz[g * 3 + 0];
    const float cy = newxyz[g * 3 + 1];
    const float cz = newxyz[g * 3 + 2];

    // ---- knn: 4-wave scan, per-wave compaction, rank-select 32 smallest
    const float* src = xyz + (size_t)b * NPTS * 3;
    int cnt = 0;
    const int jb = wv * 1024;
    for (int j0 = jb; j0 < jb + 1024; j0 += 64) {
      const int p = j0 + lane;
      const float* pp = src + p * 3;
      float d2 = d2_exact(pp[0], pp[1], pp[2], cx, cy, cz);
      bool inr = (d2 <= r2);
      ull mask = __ballot(inr);
      if (inr) {
        int pos = cnt + __popcll(mask & ((1ull << lane) - 1ull));
        if (pos < CAPW)
          H.candseg[wv][pos] = ((ull)__float_as_uint(d2) << 32) | (unsigned)p;
      }
      cnt += __popcll(mask);
    }
    if (lane == 0) H.scnt[wv] = cnt < CAPW ? cnt : CAPW;
    __syncthreads();
    const int n0 = H.scnt[0], n1 = H.scnt[1], n2 = H.scnt[2], n3 = H.scnt[3];
    const int C = n0 + n1 + n2 + n3;
    {
      int off = (wv > 0 ? n0 : 0) + (wv > 1 ? n1 : 0) + (wv > 2 ? n2 : 0);
      int myn = H.scnt[wv];
      for (int i = lane; i < myn; i += 64) H.cand2[off + i] = H.candseg[wv][i];
    }
    __syncthreads();
    for (int tt = ht; tt < C; tt += 256) {
      ull key = H.cand2[tt];
      int rank = 0;
      for (int u = 0; u < C; ++u) rank += (H.cand2[u] < key) ? 1 : 0;
      if (rank < NSAMPLE) H.sidx[rank] = (int)(key & 0xffffffffu);
    }
    if (C < NSAMPLE && wv == 0) {  // boundary fill: lowest-index outside pts
      const float* pp = src + lane * 3;
      float d2 = d2_exact(pp[0], pp[1], pp[2], cx, cy, cz);
      bool outr = !(d2 <= r2);
      ull mask = __ballot(outr);
      if (outr) {
        int pos = __popcll(mask & ((1ull << lane) - 1ull));
        if (pos < NSAMPLE - C) H.sidx[C + pos] = lane;
      }
    }
    __syncthreads();

    // ---- mlp (R3/R4-proven structure)
    if (ht < 32) {
      const float* pp = src + (size_t)H.sidx[ht] * 3;
      H.fin[ht][0] = pp[0] - cx;
      H.fin[ht][1] = pp[1] - cy;
      H.fin[ht][2] = pp[2] - cz;
      H.fin[ht][67] = 0.f;
    }
    for (int e = ht; e < 32 * FCH; e += 256) {
      int s = e >> 6;
      int c = e & 63;
      H.fin[s][3 + c] = feats[((size_t)b * NPTS + H.sidx[s]) * FCH + c];
    }
    __syncthreads();

    const int s0 = (ht >> 5) * 4;
    const int c0 = (ht & 31) * 4;
    float acc[4][4];

    // G1
    {
      float4 bv4 = *(const float4*)(b1f + c0);
#pragma unroll
      for (int i = 0; i < 4; ++i) { acc[i][0] = bv4.x; acc[i][1] = bv4.y; acc[i][2] = bv4.z; acc[i][3] = bv4.w; }
    }
    gemm_tile<67>(H.fin[s0], H.fin[s0 + 1], H.fin[s0 + 2], H.fin[s0 + 3],
                  W1f + c0, acc);
#pragma unroll
    for (int i = 0; i < 4; ++i)
#pragma unroll
      for (int j = 0; j < 4; ++j) H.bufA[s0 + i][c0 + j] = fmaxf(acc[i][j], 0.f);
    __syncthreads();

    // G2
    {
      float4 bv4 = *(const float4*)(b2f + c0);
#pragma unroll
      for (int i = 0; i < 4; ++i) { acc[i][0] = bv4.x; acc[i][1] = bv4.y; acc[i][2] = bv4.z; acc[i][3] = bv4.w; }
    }
    gemm_tile<128>(H.bufA[s0], H.bufA[s0 + 1], H.bufA[s0 + 2], H.bufA[s0 + 3],
                   W2f + c0, acc);
#pragma unroll
    for (int i = 0; i < 4; ++i)
#pragma unroll
      for (int j = 0; j < 4; ++j) H.fp[s0 + i][c0 + j] = fmaxf(acc[i][j], 0.f);
    __syncthreads();

    if (ht < HID) {
      float s = 0.f;
#pragma unroll 8
      for (int i = 0; i < 32; ++i) s += H.fp[i][ht];
      H.fm[ht] = s * (1.0f / 32.0f);
    }
    __syncthreads();

    // G3: relu( fp@W1w[3:] + (b1w + dxyz@W1w[0:3]) - fm@W1w[3:] )
    float corr[4] = {0.f, 0.f, 0.f, 0.f};
    {
      float4 bv4 = *(const float4*)(b1w + c0);
      float4 w0 = *(const float4*)(W1w + 0 * HID + c0);
      float4 w1 = *(const float4*)(W1w + 1 * HID + c0);
      float4 w2 = *(const float4*)(W1w + 2 * HID + c0);
#pragma unroll
      for (int i = 0; i < 4; ++i) {
        float dx = H.fin[s0 + i][0], dy = H.fin[s0 + i][1], dz = H.fin[s0 + i][2];
        acc[i][0] = bv4.x + dx * w0.x + dy * w1.x + dz * w2.x;
        acc[i][1] = bv4.y + dx * w0.y + dy * w1.y + dz * w2.y;
        acc[i][2] = bv4.z + dx * w0.z + dy * w1.z + dz * w2.z;
        acc[i][3] = bv4.w + dx * w0.w + dy * w1.w + dz * w2.w;
      }
    }
    gemm_tile_corr(H.fp[s0], H.fp[s0 + 1], H.fp[s0 + 2], H.fp[s0 + 3],
                   W1w + 3 * HID + c0, H.fm, acc, corr);
    __syncthreads();
#pragma unroll
    for (int i = 0; i < 4; ++i)
#pragma unroll
      for (int j = 0; j < 4; ++j)
        H.bufA[s0 + i][c0 + j] = fmaxf(acc[i][j] - corr[j], 0.f);
    __syncthreads();

    // G4
    {
      float4 bv4 = *(const float4*)(b2w + c0);
#pragma unroll
      for (int i = 0; i < 4; ++i) { acc[i][0] = bv4.x; acc[i][1] = bv4.y; acc[i][2] = bv4.z; acc[i][3] = bv4.w; }
    }
    gemm_tile<128>(H.bufA[s0], H.bufA[s0 + 1], H.bufA[s0 + 2], H.bufA[s0 + 3],
                   W2w + c0, acc);
    {
      float part[4] = {0.f, 0.f, 0.f, 0.f};
#pragma unroll
      for (int i = 0; i < 4; ++i)
#pragma unroll
        for (int j = 0; j < 4; ++j) {
          float al = 1.0f / (1.0f + __expf(-acc[i][j]));
          part[j] += al * H.fp[s0 + i][c0 + j];
        }
      __syncthreads();  // fin dead -> reuse as 8xHID reduction buffer
      float* redp = &H.fin[0][0];
      redp[(ht >> 5) * HID + c0 + 0] = part[0];
      redp[(ht >> 5) * HID + c0 + 1] = part[1];
      redp[(ht >> 5) * HID + c0 + 2] = part[2];
      redp[(ht >> 5) * HID + c0 + 3] = part[3];
    }
    __syncthreads();
    if (ht < HID) {
      float* redp = &H.fin[0][0];
      float s = 0.f;
#pragma unroll
      for (int w = 0; w < 8; ++w) s += redp[w * HID + ht];
      fout[(size_t)g * HID + ht] = s;
    }
    __syncthreads();  // LDS fully consumed before next ticket
  }
}

// ---------------------------------------------------------------- fused
__global__ __launch_bounds__(512, 1) void sa_fused_kernel(
    const float* __restrict__ xyz, const float* __restrict__ feats,
    const float* __restrict__ W1f, const float* __restrict__ b1f,
    const float* __restrict__ W2f, const float* __restrict__ b2f,
    const float* __restrict__ W1w, const float* __restrict__ b1w,
    const float* __restrict__ W2w, const float* __restrict__ b2w,
    float* __restrict__ newxyz, float* __restrict__ fout, int* ctrl) {
  __shared__ SMemU sm;
  int* progress = ctrl;    // [0..7]
  int* ticket = ctrl + 8;  // [8]
  if (blockIdx.x < NB) {
    run_fps(xyz, newxyz, progress, blockIdx.x, sm.p);
    __syncthreads();  // producer joins consumer pool for the tail
  }
  run_consumer(xyz, feats, W1f, b1f, W2f, b2f, W1w, b1w, W2w, b2w, newxyz,
               fout, progress, ticket, sm.c);
}

extern "C" void kernel_launch(void* const* d_in, const int* in_sizes, int n_in,
                              void* d_out, int out_size, void* d_ws, size_t ws_size,
                              hipStream_t stream) {
  const float* xyz = (const float*)d_in[0];
  const float* feats = (const float*)d_in[1];
  const float* W1f = (const float*)d_in[2];
  const float* b1f = (const float*)d_in[3];
  const float* W2f = (const float*)d_in[4];
  const float* b2f = (const float*)d_in[5];
  const float* W1w = (const float*)d_in[6];
  const float* b1w = (const float*)d_in[7];
  const float* W2w = (const float*)d_in[8];
  const float* b2w = (const float*)d_in[9];

  float* newxyz = (float*)d_out;                          // (8,1024,3)
  float* fout = (float*)d_out + (size_t)NB * NPOINT * 3;  // (8,1024,128)
  int* ctrl = (int*)d_ws;  // progress[8] + ticket[1]

  hipMemsetAsync(ctrl, 0, 64, stream);
  // 256 blocks x 512 thr, 88KB LDS -> structurally 1 block/CU: producers
  // solo by construction (no dispatch-mapping assumptions), consumer CUs
  // carry 8 waves via two independent R4-style pipelines per block.
  sa_fused_kernel<<<256, 512, 0, stream>>>(xyz, feats, W1f, b1f, W2f, b2f,
                                           W1w, b1w, W2w, b2w, newxyz, fout,
                                           ctrl);
}